// Round 8
// baseline (884.195 us; speedup 1.0000x reference)
//
#include <hip/hip_runtime.h>

#define NN 100000      // N_NODES
#define NE 3200000     // N_EDGES
#define NF 128         // N_F
#define NH 128         // HIDDEN
#define NP 8           // N_PRED
#define NG 64          // N_GRAPHS

#define PT 64          // k_pool node tile
#define GP 1024        // k_pool grid (4 blocks/CU at 40 KB LDS)

#define SCAN_B 1024
#define SCAN_NBLK 98   // ceil(100000/1024)

// f32 -> bf16 (RNE), bf16 -> f32 (shift)
__device__ __forceinline__ unsigned short f2bf(float f) {
    unsigned u = __float_as_uint(f);
    return (unsigned short)((u + 0x7fffu + ((u >> 16) & 1u)) >> 16);
}
__device__ __forceinline__ float bf2f(unsigned short b) {
    return __uint_as_float((unsigned)b << 16);
}

// ---------------- init: cnt, psum, rcnt, deg ----------------
__global__ void k_init(float* __restrict__ cnt, float* __restrict__ psum,
                       int* __restrict__ rcnt, float* __restrict__ deg) {
    int i = blockIdx.x * blockDim.x + threadIdx.x;
    if (i < NG) cnt[i] = 0.0f;
    if (i < NG * NH) psum[i] = 0.0f;
    if (i < NN) { rcnt[i] = 0; deg[i] = 0.0f; }
}

// ---------------- edge pass 1: degree (unweighted row, weighted col) ----------------
// Unstable-sort redesign: scattered fire-and-forget global atomics replace the
// per-slice LDS histogram machinery (H/Hd arrays, k_hist/k_deg_hist/k_reduce/k_base).
__global__ __launch_bounds__(256) void k_deg2(const int* __restrict__ row,
                                              const int* __restrict__ col,
                                              const float* __restrict__ wt,
                                              int* __restrict__ rcnt,
                                              float* __restrict__ deg) {
    int i = blockIdx.x * blockDim.x + threadIdx.x;   // 8 edges per thread
    if (i >= NE / 8) return;
    const int4*   r4 = (const int4*)row;
    const int4*   c4 = (const int4*)col;
    const float4* w4 = (const float4*)wt;
    int4 ra = r4[2 * i], rb = r4[2 * i + 1];
    int4 ca = c4[2 * i], cb = c4[2 * i + 1];
    float4 wa = w4[2 * i], wb = w4[2 * i + 1];
    int rs[8] = {ra.x, ra.y, ra.z, ra.w, rb.x, rb.y, rb.z, rb.w};
    int cs[8] = {ca.x, ca.y, ca.z, ca.w, cb.x, cb.y, cb.z, cb.w};
    float ww[8] = {wa.x, wa.y, wa.z, wa.w, wb.x, wb.y, wb.z, wb.w};
#pragma unroll
    for (int j = 0; j < 8; ++j) {
        atomicAdd(&rcnt[rs[j]], 1);
        atomicAdd(&deg[cs[j]], ww[j]);
    }
}

// ---------------- per-graph node counts ----------------
__global__ void k_cnt(const int* __restrict__ batch, float* __restrict__ cnt) {
    __shared__ float c[NG];
    int t = threadIdx.x;
    if (t < NG) c[t] = 0.0f;
    __syncthreads();
    int i = blockIdx.x * blockDim.x + t;
    if (i < NN) atomicAdd(&c[batch[i]], 1.0f);
    __syncthreads();
    if (t < NG && c[t] != 0.0f) atomicAdd(&cnt[t], c[t]);
}

// ---------------- dinv[r] = rsqrt(1 + deg[r]) ----------------
__global__ void k_dinv(const float* __restrict__ deg, float* __restrict__ dinv) {
    int r = blockIdx.x * blockDim.x + threadIdx.x;
    if (r < NN) dinv[r] = rsqrtf(1.0f + deg[r]);
}

// ---------------- scan pass 1 ----------------
__global__ __launch_bounds__(SCAN_B) void k_scan1(const int* __restrict__ rcnt,
                                                  int* __restrict__ px,
                                                  int* __restrict__ bsum) {
    __shared__ int s[SCAN_B];
    int t = threadIdx.x;
    int i = blockIdx.x * SCAN_B + t;
    int v = (i < NN) ? rcnt[i] : 0;
    s[t] = v;
    __syncthreads();
    for (int off = 1; off < SCAN_B; off <<= 1) {
        int x = (t >= off) ? s[t - off] : 0;
        __syncthreads();
        s[t] += x;
        __syncthreads();
    }
    px[i] = s[t] - v;
    if (t == SCAN_B - 1) bsum[blockIdx.x] = s[t];
}

// ---------------- scan pass 2 ----------------
__global__ void k_scan2(const int* __restrict__ bsum, int* __restrict__ bofs) {
    if (threadIdx.x == 0) {
        int acc = 0;
        for (int b = 0; b < SCAN_NBLK; ++b) { bofs[b] = acc; acc += bsum[b]; }
    }
}

// ---------------- scan pass 3: rowptr + cursor copy ----------------
__global__ void k_scan3(const int* __restrict__ px, const int* __restrict__ bofs,
                        int* __restrict__ rowptr, int* __restrict__ cursor) {
    int i = blockIdx.x * blockDim.x + threadIdx.x;
    if (i > NN) return;
    int v = px[i] + bofs[i >> 10];
    rowptr[i] = v;
    if (i < NN) cursor[i] = v;
}

// ---------------- edge pass 2: unstable counting-sort scatter ----------------
// pos = atomicAdd(cursor[row]); order within a row is arbitrary (sums commute,
// f32 accumulation -> reorder noise << bf16 threshold).
__global__ __launch_bounds__(256) void k_sort2(const int* __restrict__ row,
                                               const int* __restrict__ col,
                                               const float* __restrict__ wt,
                                               int* __restrict__ cursor,
                                               const float* __restrict__ dinv,
                                               float2* __restrict__ pack) {
    int i = blockIdx.x * blockDim.x + threadIdx.x;   // 8 edges per thread
    if (i >= NE / 8) return;
    const int4*   r4 = (const int4*)row;
    const int4*   c4 = (const int4*)col;
    const float4* w4 = (const float4*)wt;
    int4 ra = r4[2 * i], rb = r4[2 * i + 1];
    int4 ca = c4[2 * i], cb = c4[2 * i + 1];
    float4 wa = w4[2 * i], wb = w4[2 * i + 1];
    int rs[8] = {ra.x, ra.y, ra.z, ra.w, rb.x, rb.y, rb.z, rb.w};
    int cs[8] = {ca.x, ca.y, ca.z, ca.w, cb.x, cb.y, cb.z, cb.w};
    float ww[8] = {wa.x, wa.y, wa.z, wa.w, wb.x, wb.y, wb.z, wb.w};
#pragma unroll
    for (int j = 0; j < 8; ++j) {
        int pos = atomicAdd(&cursor[rs[j]], 1);
        pack[pos] = make_float2(__int_as_float(cs[j]),
                                dinv[rs[j]] * ww[j] * dinv[cs[j]]);
    }
}

// nontemporal u64 load of a pack entry: low 32 = col bits, high 32 = weight
__device__ __forceinline__ void pk_nt(const float2* __restrict__ pack, int idx,
                                      int& cc, float& w) {
    unsigned long long pu =
        __builtin_nontemporal_load((const unsigned long long*)pack + idx);
    cc = (int)(unsigned)pu;
    w = __uint_as_float((unsigned)(pu >> 32));
}

// ---------------- hop 1 (bf16 out): 32 edges/iter, 4 batch-gathers in flight ----------------
// lane = (edge-slot es = lane>>3, graph-group gg = lane&7); self-term only es==0.
__global__ void k_q1_gather(const int* __restrict__ rowptr, const float2* __restrict__ pack,
                            const int* __restrict__ batch, const float* __restrict__ dinv,
                            unsigned short* __restrict__ Q) {
    int wid = (blockIdx.x * blockDim.x + threadIdx.x) >> 6;
    int lane = threadIdx.x & 63;
    if (wid >= NN) return;
    int es = lane >> 3;      // edge slot within 8-batch
    int gg = lane & 7;       // graph group: graphs gg*8 .. gg*8+7
    int beg = rowptr[wid], end = rowptr[wid + 1];
    float d = dinv[wid];
    int bself = batch[wid];
    float dd = d * d;
    float acc[8];
#pragma unroll
    for (int i = 0; i < 8; ++i)
        acc[i] = (es == 0 && bself == gg * 8 + i) ? dd : 0.0f;

    if (beg < end) {
        int last = end - 1;
        for (int e = beg; e < end; e += 32) {
            int i0 = e + es, i1 = e + 8 + es, i2 = e + 16 + es, i3 = e + 24 + es;
            int c0, c1, c2, c3; float w0, w1, w2, w3;
            pk_nt(pack, min(i0, last), c0, w0);
            pk_nt(pack, min(i1, last), c1, w1);
            pk_nt(pack, min(i2, last), c2, w2);
            pk_nt(pack, min(i3, last), c3, w3);
            if (i0 > last) w0 = 0.0f;
            if (i1 > last) w1 = 0.0f;
            if (i2 > last) w2 = 0.0f;
            if (i3 > last) w3 = 0.0f;
            int b0 = batch[c0];
            int b1 = batch[c1];
            int b2 = batch[c2];
            int b3 = batch[c3];
#pragma unroll
            for (int i = 0; i < 8; ++i) {
                int g = gg * 8 + i;
                acc[i] += (b0 == g) ? w0 : 0.0f;
                acc[i] += (b1 == g) ? w1 : 0.0f;
                acc[i] += (b2 == g) ? w2 : 0.0f;
                acc[i] += (b3 == g) ? w3 : 0.0f;
            }
        }
    }
#pragma unroll
    for (int m = 8; m <= 32; m <<= 1)
#pragma unroll
        for (int i = 0; i < 8; ++i) acc[i] += __shfl_xor(acc[i], m, 64);
    if (es == 0) {
        uint4 o;
        o.x = (unsigned)f2bf(acc[0]) | ((unsigned)f2bf(acc[1]) << 16);
        o.y = (unsigned)f2bf(acc[2]) | ((unsigned)f2bf(acc[3]) << 16);
        o.z = (unsigned)f2bf(acc[4]) | ((unsigned)f2bf(acc[5]) << 16);
        o.w = (unsigned)f2bf(acc[6]) | ((unsigned)f2bf(acc[7]) << 16);
        ((uint4*)Q)[(size_t)wid * 8 + gg] = o;
    }
}

// ---------------- hops 2,3 (bf16 in/out): 32 edges/iter, 4 row-gathers in flight ----------------
// Monolithic 64-graph form: at the random-line L2-fill ceiling (~3.6 TB/s on ~330 MB);
// plane-split regressed 4x overhead (round 5) — do not revisit.
__global__ void k_hop_gather(const int* __restrict__ rowptr, const float2* __restrict__ pack,
                             const float* __restrict__ dinv,
                             const unsigned short* __restrict__ Qin,
                             unsigned short* __restrict__ Qout) {
    int wid = (blockIdx.x * blockDim.x + threadIdx.x) >> 6;
    int lane = threadIdx.x & 63;
    if (wid >= NN) return;
    int es = lane >> 3;
    int gg = lane & 7;
    int beg = rowptr[wid], end = rowptr[wid + 1];
    float d = dinv[wid];
    const uint4* Q4 = (const uint4*)Qin;   // row r, group gg at index r*8+gg

    float acc[8];
    if (es == 0) {
        uint4 qs = Q4[(size_t)wid * 8 + gg];
        float dd = d * d;
        acc[0] = dd * __uint_as_float(qs.x << 16);
        acc[1] = dd * __uint_as_float(qs.x & 0xffff0000u);
        acc[2] = dd * __uint_as_float(qs.y << 16);
        acc[3] = dd * __uint_as_float(qs.y & 0xffff0000u);
        acc[4] = dd * __uint_as_float(qs.z << 16);
        acc[5] = dd * __uint_as_float(qs.z & 0xffff0000u);
        acc[6] = dd * __uint_as_float(qs.w << 16);
        acc[7] = dd * __uint_as_float(qs.w & 0xffff0000u);
    } else {
#pragma unroll
        for (int i = 0; i < 8; ++i) acc[i] = 0.0f;
    }

    if (beg < end) {
        int last = end - 1;
        for (int e = beg; e < end; e += 32) {
            int i0 = e + es, i1 = e + 8 + es, i2 = e + 16 + es, i3 = e + 24 + es;
            int c0, c1, c2, c3; float w0, w1, w2, w3;
            pk_nt(pack, min(i0, last), c0, w0);
            pk_nt(pack, min(i1, last), c1, w1);
            pk_nt(pack, min(i2, last), c2, w2);
            pk_nt(pack, min(i3, last), c3, w3);
            if (i0 > last) w0 = 0.0f;
            if (i1 > last) w1 = 0.0f;
            if (i2 > last) w2 = 0.0f;
            if (i3 > last) w3 = 0.0f;
            uint4 q0 = Q4[(size_t)c0 * 8 + gg];
            uint4 q1 = Q4[(size_t)c1 * 8 + gg];
            uint4 q2 = Q4[(size_t)c2 * 8 + gg];
            uint4 q3 = Q4[(size_t)c3 * 8 + gg];
            acc[0] += w0 * __uint_as_float(q0.x << 16);
            acc[1] += w0 * __uint_as_float(q0.x & 0xffff0000u);
            acc[2] += w0 * __uint_as_float(q0.y << 16);
            acc[3] += w0 * __uint_as_float(q0.y & 0xffff0000u);
            acc[4] += w0 * __uint_as_float(q0.z << 16);
            acc[5] += w0 * __uint_as_float(q0.z & 0xffff0000u);
            acc[6] += w0 * __uint_as_float(q0.w << 16);
            acc[7] += w0 * __uint_as_float(q0.w & 0xffff0000u);
            acc[0] += w1 * __uint_as_float(q1.x << 16);
            acc[1] += w1 * __uint_as_float(q1.x & 0xffff0000u);
            acc[2] += w1 * __uint_as_float(q1.y << 16);
            acc[3] += w1 * __uint_as_float(q1.y & 0xffff0000u);
            acc[4] += w1 * __uint_as_float(q1.z << 16);
            acc[5] += w1 * __uint_as_float(q1.z & 0xffff0000u);
            acc[6] += w1 * __uint_as_float(q1.w << 16);
            acc[7] += w1 * __uint_as_float(q1.w & 0xffff0000u);
            acc[0] += w2 * __uint_as_float(q2.x << 16);
            acc[1] += w2 * __uint_as_float(q2.x & 0xffff0000u);
            acc[2] += w2 * __uint_as_float(q2.y << 16);
            acc[3] += w2 * __uint_as_float(q2.y & 0xffff0000u);
            acc[4] += w2 * __uint_as_float(q2.z << 16);
            acc[5] += w2 * __uint_as_float(q2.z & 0xffff0000u);
            acc[6] += w2 * __uint_as_float(q2.w << 16);
            acc[7] += w2 * __uint_as_float(q2.w & 0xffff0000u);
            acc[0] += w3 * __uint_as_float(q3.x << 16);
            acc[1] += w3 * __uint_as_float(q3.x & 0xffff0000u);
            acc[2] += w3 * __uint_as_float(q3.y << 16);
            acc[3] += w3 * __uint_as_float(q3.y & 0xffff0000u);
            acc[4] += w3 * __uint_as_float(q3.z << 16);
            acc[5] += w3 * __uint_as_float(q3.z & 0xffff0000u);
            acc[6] += w3 * __uint_as_float(q3.w << 16);
            acc[7] += w3 * __uint_as_float(q3.w & 0xffff0000u);
        }
    }
#pragma unroll
    for (int m = 8; m <= 32; m <<= 1)
#pragma unroll
        for (int i = 0; i < 8; ++i) acc[i] += __shfl_xor(acc[i], m, 64);
    if (es == 0) {
        uint4 o;
        o.x = (unsigned)f2bf(acc[0]) | ((unsigned)f2bf(acc[1]) << 16);
        o.y = (unsigned)f2bf(acc[2]) | ((unsigned)f2bf(acc[3]) << 16);
        o.z = (unsigned)f2bf(acc[4]) | ((unsigned)f2bf(acc[5]) << 16);
        o.w = (unsigned)f2bf(acc[6]) | ((unsigned)f2bf(acc[7]) << 16);
        ((uint4*)Qout)[(size_t)wid * 8 + gg] = o;
    }
}

// ---------------- pool: per-block partial[g][f] = sum_n Q3[n][g]*x[n][f] ----------------
// 40 KB LDS -> 4 blocks/CU; NO trailing atomics (plain float4 partial stores).
__global__ __launch_bounds__(256) void k_pool(const unsigned short* __restrict__ Q,
                                              const float* __restrict__ x,
                                              float* __restrict__ partial) {
    __shared__ unsigned short qsh[PT * NG];   // 8 KB (bf16)
    __shared__ float xs[PT * NF];             // 32 KB
    int t = threadIdx.x;
    int f4 = (t & 31) << 2;
    int g0 = (t >> 5) << 3;
    float4 acc[8];
#pragma unroll
    for (int i = 0; i < 8; ++i) acc[i] = make_float4(0.f, 0.f, 0.f, 0.f);

    const int NT = (NN + PT - 1) / PT;   // 1563
    for (int tile = blockIdx.x; tile < NT; tile += GP) {
        int n0 = tile * PT;
        int nt = min(PT, NN - n0);
        const uint4*  Q4 = (const uint4*)(Q + (size_t)n0 * NG);
        const float4* X4 = (const float4*)(x + (size_t)n0 * NF);
        uint4*  qs4 = (uint4*)qsh;
        float4* xs4 = (float4*)xs;
        for (int i = t; i < nt * (NG / 8); i += 256) qs4[i] = Q4[i];
        for (int i = t; i < nt * (NF / 4); i += 256) xs4[i] = X4[i];
        __syncthreads();
        for (int n = 0; n < nt; ++n) {
            float4 xv = *(const float4*)&xs[n * NF + f4];
            uint4 qu = *(const uint4*)&qsh[n * NG + g0];
            float qv[8];
            qv[0] = __uint_as_float(qu.x << 16);
            qv[1] = __uint_as_float(qu.x & 0xffff0000u);
            qv[2] = __uint_as_float(qu.y << 16);
            qv[3] = __uint_as_float(qu.y & 0xffff0000u);
            qv[4] = __uint_as_float(qu.z << 16);
            qv[5] = __uint_as_float(qu.z & 0xffff0000u);
            qv[6] = __uint_as_float(qu.w << 16);
            qv[7] = __uint_as_float(qu.w & 0xffff0000u);
#pragma unroll
            for (int i = 0; i < 8; ++i) {
                acc[i].x += qv[i] * xv.x;
                acc[i].y += qv[i] * xv.y;
                acc[i].z += qv[i] * xv.z;
                acc[i].w += qv[i] * xv.w;
            }
        }
        __syncthreads();
    }
    float* pb = partial + (size_t)blockIdx.x * (NG * NF);
#pragma unroll
    for (int i = 0; i < 8; ++i)
        *(float4*)&pb[(g0 + i) * NF + f4] = acc[i];
}

// ---------------- reduce GP partial slabs -> psum (8-way split-K) ----------------
__global__ void k_red(const float* __restrict__ partial, float* __restrict__ psum) {
    int gid = blockIdx.x * blockDim.x + threadIdx.x;   // 65536 threads
    int idx = gid & (NG * NF - 1);
    int j = gid >> 13;                                 // 0..7
    float acc = 0.0f;
    for (int b = j; b < GP; b += 8)
        acc += partial[(size_t)b * (NG * NF) + idx];
    atomicAdd(&psum[idx], acc);
}

// ---------------- final: fold both linears ----------------
__global__ void k_final(const float* __restrict__ psum, const float* __restrict__ cnt,
                        const float* __restrict__ Wc, const float* __restrict__ bc,
                        const float* __restrict__ Wl, const float* __restrict__ bl,
                        float* __restrict__ out) {
    __shared__ float M[NP * NH];
    __shared__ float bias[NP];
    int t = threadIdx.x;
    for (int idx = t; idx < NP * NH; idx += 256) {
        int p = idx >> 7, f = idx & 127;
        float s = 0.0f;
        for (int h = 0; h < NH; ++h) s += Wl[p * NH + h] * Wc[h * NF + f];
        M[idx] = s;
    }
    if (t < NP) {
        float s = bl[t];
        for (int h = 0; h < NH; ++h) s += Wl[t * NH + h] * bc[h];
        bias[t] = s;
    }
    __syncthreads();
    for (int idx = t; idx < NG * NP; idx += 256) {
        int g = idx >> 3, p = idx & 7;
        float inv = 1.0f / fmaxf(cnt[g], 1.0f);
        float s = 0.0f;
        for (int f = 0; f < NF; ++f) s += psum[g * NF + f] * M[p * NH + f];
        out[idx] = s * inv + bias[p];
    }
}

extern "C" void kernel_launch(void* const* d_in, const int* in_sizes, int n_in,
                              void* d_out, int out_size, void* d_ws, size_t ws_size,
                              hipStream_t stream) {
    const float* x     = (const float*)d_in[0];
    const int*   ei    = (const int*)d_in[1];
    const float* ea    = (const float*)d_in[2];
    const int*   batch = (const int*)d_in[3];
    const float* Wc    = (const float*)d_in[4];
    const float* bc    = (const float*)d_in[5];
    const float* Wl    = (const float*)d_in[6];
    const float* bl    = (const float*)d_in[7];
    const int* row = ei;           // edge_index[0]
    const int* col = ei + NE;      // edge_index[1]
    float* out = (float*)d_out;

    // ---- workspace (same ~77.7 MB footprint / layout as round 7) ----
    // pack region also hosts scan scratch + deg (all dead before k_sort2 writes pack).
    // cursor lives at start of the old H region; dead before q1 writes Qa there.
    // partial (33.6 MB) spans Qb + old-Hd region (both dead before k_pool).
    float* ws     = (float*)d_ws;
    float*  dinv   = ws;                          // NN floats
    int*    rowptr = (int*)(dinv + NN);           // NN+4 ints
    float*  cnt    = (float*)(rowptr + NN + 4);   // NG
    float*  psum   = cnt + NG;                    // NG*NH
    float2* pack   = (float2*)(psum + NG * NH);   // NE float2 (25.6 MB)
    unsigned* H    = (unsigned*)(pack + NE);      // 25.6 MB region (Qa + cursor alias)
    unsigned short* Qa = (unsigned short*)H;              // NN*64 bf16 (12.8 MB)
    unsigned short* Qb = Qa + (size_t)NN * NG;            // NN*64 bf16 (12.8 MB)
    float* partial = (float*)Qb;                  // GP*NG*NF f32 (33.6 MB)
    // scan scratch + degree arrays alias pack (dead before k_sort2):
    int*   rcnt = (int*)pack;                     // NN ints (scan input)
    int*   px   = rcnt + SCAN_NBLK * SCAN_B;
    int*   bsum = px + SCAN_NBLK * SCAN_B;
    int*   bofs = bsum + SCAN_NBLK;
    float* deg  = (float*)(bofs + SCAN_NBLK);     // NN floats
    int*   cursor = (int*)H;                      // NN ints (dead before q1 writes Qa)

    const int B = 256;
    int gN  = (NN + B - 1) / B;                          // 391
    int gE  = (NE / 8 + B - 1) / B;                      // 1563
    int gW  = (int)(((long long)NN * 64 + B - 1) / B);   // 25000

    k_init<<<gN, B, 0, stream>>>(cnt, psum, rcnt, deg);
    k_deg2<<<gE, B, 0, stream>>>(row, col, ea, rcnt, deg);
    k_cnt<<<gN, B, 0, stream>>>(batch, cnt);
    k_dinv<<<gN, B, 0, stream>>>(deg, dinv);

    k_scan1<<<SCAN_NBLK, SCAN_B, 0, stream>>>(rcnt, px, bsum);
    k_scan2<<<1, 64, 0, stream>>>(bsum, bofs);
    k_scan3<<<(NN + 1 + SCAN_B - 1) / SCAN_B, SCAN_B, 0, stream>>>(px, bofs, rowptr, cursor);
    k_sort2<<<gE, B, 0, stream>>>(row, col, ea, cursor, dinv, pack);

    // NOTE: k_q1_gather overwrites the H region (as Qa) — cursor is dead after k_sort2.
    k_q1_gather<<<gW, B, 0, stream>>>(rowptr, pack, batch, dinv, Qa);
    k_hop_gather<<<gW, B, 0, stream>>>(rowptr, pack, dinv, Qa, Qb);
    k_hop_gather<<<gW, B, 0, stream>>>(rowptr, pack, dinv, Qb, Qa);

    // NOTE: k_pool writes partial over Qb (dead); reads Qa (live).
    k_pool<<<GP, B, 0, stream>>>(Qa, x, partial);
    k_red<<<256, B, 0, stream>>>(partial, psum);
    k_final<<<1, B, 0, stream>>>(psum, cnt, Wc, bc, Wl, bl, out);
}

// Round 9
// 602.866 us; speedup vs baseline: 1.4667x; 1.4667x over previous
//
#include <hip/hip_runtime.h>

#define NN 100000      // N_NODES
#define NE 3200000     // N_EDGES
#define NF 128         // N_F
#define NH 128         // HIDDEN
#define NP 8           // N_PRED
#define NG 64          // N_GRAPHS

#define CS_H 8000      // merged-hist bins/chunk (8 B/bin -> 64 KB LDS, 2 blocks/CU)
#define NC_H 13        // ceil(100000/8000)
#define CS_S 10000     // k_sort bins/chunk (40 KB LDS -> 4 blocks/CU)
#define NC_S 10        // 10*10000 = NN exactly
#define NW 64          // edge slices; idx = c*NW+w -> slice w pinned to XCD w%8
#define ES (NE / NW)   // 50000 edges per slice (divisible by 8)

#define PT 64          // k_pool node tile
#define GP 1024        // k_pool grid (4 blocks/CU at 40 KB LDS)

#define SCAN_B 1024
#define SCAN_NBLK 98   // ceil(100000/1024)

// f32 -> bf16 (RNE), bf16 -> f32 (shift)
__device__ __forceinline__ unsigned short f2bf(float f) {
    unsigned u = __float_as_uint(f);
    return (unsigned short)((u + 0x7fffu + ((u >> 16) & 1u)) >> 16);
}
__device__ __forceinline__ float bf2f(unsigned short b) {
    return __uint_as_float((unsigned)b << 16);
}

// ---------------- init: cnt, psum ----------------
__global__ void k_init(float* __restrict__ cnt, float* __restrict__ psum) {
    int i = blockIdx.x * blockDim.x + threadIdx.x;
    if (i < NG) cnt[i] = 0.0f;
    if (i < NG * NH) psum[i] = 0.0f;
}

// ---------------- merged histogram: H[w][r] (row count) + Hd[w][c] (weighted col) ----------------
// One pass over the slice instead of two separate kernels (round-8 lesson: global
// scatter-atomics are a 294-us wall; LDS histograms are the right structure).
__global__ __launch_bounds__(256) void k_hist2(const int* __restrict__ row,
                                               const int* __restrict__ col,
                                               const float* __restrict__ wt,
                                               unsigned* __restrict__ H,
                                               float* __restrict__ Hd) {
    __shared__ unsigned hist[CS_H];   // 32 KB
    __shared__ float    dh[CS_H];     // 32 KB
    int w = blockIdx.x % NW, c = blockIdx.x / NW;
    int rbase = c * CS_H;
    int nb = (rbase + CS_H <= NN) ? CS_H : (NN - rbase);
    for (int i = threadIdx.x; i < nb; i += 256) { hist[i] = 0u; dh[i] = 0.0f; }
    __syncthreads();
    const int4*   r4 = (const int4*)(row + (size_t)w * ES);
    const int4*   c4 = (const int4*)(col + (size_t)w * ES);
    const float4* w4 = (const float4*)(wt + (size_t)w * ES);
    for (int i = threadIdx.x; i < ES / 8; i += 256) {
        int4 ra = r4[2 * i], rb = r4[2 * i + 1];
        int4 ca = c4[2 * i], cb = c4[2 * i + 1];
        float4 wa = w4[2 * i], wb = w4[2 * i + 1];
        int rs[8] = {ra.x, ra.y, ra.z, ra.w, rb.x, rb.y, rb.z, rb.w};
        int cs[8] = {ca.x, ca.y, ca.z, ca.w, cb.x, cb.y, cb.z, cb.w};
        float ww[8] = {wa.x, wa.y, wa.z, wa.w, wb.x, wb.y, wb.z, wb.w};
#pragma unroll
        for (int j = 0; j < 8; ++j) {
            unsigned rr = (unsigned)(rs[j] - rbase);
            if (rr < (unsigned)nb) atomicAdd(&hist[rr], 1u);
            unsigned cc = (unsigned)(cs[j] - rbase);
            if (cc < (unsigned)nb) atomicAdd(&dh[cc], ww[j]);
        }
    }
    __syncthreads();
    for (int i = threadIdx.x; i < nb; i += 256) {
        H [(size_t)w * NN + rbase + i] = hist[i];
        Hd[(size_t)w * NN + rbase + i] = dh[i];
    }
}

// ---------------- per-graph node counts ----------------
__global__ void k_cnt(const int* __restrict__ batch, float* __restrict__ cnt) {
    __shared__ float c[NG];
    int t = threadIdx.x;
    if (t < NG) c[t] = 0.0f;
    __syncthreads();
    int i = blockIdx.x * blockDim.x + t;
    if (i < NN) atomicAdd(&c[batch[i]], 1.0f);
    __syncthreads();
    if (t < NG && c[t] != 0.0f) atomicAdd(&cnt[t], c[t]);
}

// ---------------- reduce slices: rcnt[r] = sum_w H, dinv[r] = rsqrt(1 + sum_w Hd) ----------------
__global__ void k_reduce(const unsigned* __restrict__ H, const float* __restrict__ Hd,
                         int* __restrict__ rcnt, float* __restrict__ dinv) {
    int r = blockIdx.x * blockDim.x + threadIdx.x;
    if (r >= NN) return;
    unsigned s = 0;
    float d = 1.0f;   // self-loop weight
#pragma unroll
    for (int w = 0; w < NW; ++w) {
        s += H[(size_t)w * NN + r];
        d += Hd[(size_t)w * NN + r];
    }
    rcnt[r] = (int)s;
    dinv[r] = rsqrtf(d);
}

// ---------------- scan pass 1 ----------------
__global__ __launch_bounds__(SCAN_B) void k_scan1(const int* __restrict__ rcnt,
                                                  int* __restrict__ px,
                                                  int* __restrict__ bsum) {
    __shared__ int s[SCAN_B];
    int t = threadIdx.x;
    int i = blockIdx.x * SCAN_B + t;
    int v = (i < NN) ? rcnt[i] : 0;
    s[t] = v;
    __syncthreads();
    for (int off = 1; off < SCAN_B; off <<= 1) {
        int x = (t >= off) ? s[t - off] : 0;
        __syncthreads();
        s[t] += x;
        __syncthreads();
    }
    px[i] = s[t] - v;
    if (t == SCAN_B - 1) bsum[blockIdx.x] = s[t];
}

// ---------------- scan pass 2 ----------------
__global__ void k_scan2(const int* __restrict__ bsum, int* __restrict__ bofs) {
    if (threadIdx.x == 0) {
        int acc = 0;
        for (int b = 0; b < SCAN_NBLK; ++b) { bofs[b] = acc; acc += bsum[b]; }
    }
}

// ---------------- scan pass 3: rowptr ----------------
__global__ void k_scan3(const int* __restrict__ px, const int* __restrict__ bofs,
                        int* __restrict__ rowptr) {
    int i = blockIdx.x * blockDim.x + threadIdx.x;
    if (i > NN) return;
    rowptr[i] = px[i] + bofs[i >> 10];
}

// ---------------- H -> per-(row,slice) base offsets (in place) ----------------
__global__ void k_base(const int* __restrict__ rowptr, unsigned* __restrict__ H) {
    int r = blockIdx.x * blockDim.x + threadIdx.x;
    if (r >= NN) return;
    unsigned acc = (unsigned)rowptr[r];
#pragma unroll
    for (int w = 0; w < NW; ++w) {
        unsigned v = H[(size_t)w * NN + r];
        H[(size_t)w * NN + r] = acc;
        acc += v;
    }
}

// ---------------- stable counting-sort scatter (round-7 proven) ----------------
// CS_S=10000 -> 40 KB LDS -> 4 blocks/CU; idx=c*NW+w keeps slice w on XCD w%8
// (read dedup). Plain cached loads (nt loads regressed FETCH 35->167 MB, round 6).
__global__ __launch_bounds__(256) void k_sort(const int* __restrict__ row,
                                              const int* __restrict__ col,
                                              const float* __restrict__ wt,
                                              const unsigned* __restrict__ B,
                                              const float* __restrict__ dinv,
                                              float2* __restrict__ pack) {
    __shared__ unsigned basel[CS_S];
    int w = blockIdx.x % NW, c = blockIdx.x / NW;
    int rbase = c * CS_S;
    int nb = (rbase + CS_S <= NN) ? CS_S : (NN - rbase);
    for (int i = threadIdx.x; i < nb; i += 256)
        basel[i] = B[(size_t)w * NN + rbase + i];
    __syncthreads();
    const int4*   r4 = (const int4*)(row + (size_t)w * ES);
    const int4*   c4 = (const int4*)(col + (size_t)w * ES);
    const float4* w4 = (const float4*)(wt + (size_t)w * ES);
    for (int i = threadIdx.x; i < ES / 8; i += 256) {
        int4 ra = r4[2 * i], rb = r4[2 * i + 1];
        int4 ca = c4[2 * i], cb = c4[2 * i + 1];
        float4 wa = w4[2 * i], wb = w4[2 * i + 1];
        int rs[8] = {ra.x, ra.y, ra.z, ra.w, rb.x, rb.y, rb.z, rb.w};
        int cs[8] = {ca.x, ca.y, ca.z, ca.w, cb.x, cb.y, cb.z, cb.w};
        float ww[8] = {wa.x, wa.y, wa.z, wa.w, wb.x, wb.y, wb.z, wb.w};
#pragma unroll
        for (int j = 0; j < 8; ++j) {
            unsigned rr = (unsigned)(rs[j] - rbase);
            if (rr < (unsigned)nb) {
                unsigned pos = atomicAdd(&basel[rr], 1u);
                pack[pos] = make_float2(__int_as_float(cs[j]),
                                        dinv[rs[j]] * ww[j] * dinv[cs[j]]);
            }
        }
    }
}

// nontemporal u64 load of a pack entry: low 32 = col bits, high 32 = weight
__device__ __forceinline__ void pk_nt(const float2* __restrict__ pack, int idx,
                                      int& cc, float& w) {
    unsigned long long pu =
        __builtin_nontemporal_load((const unsigned long long*)pack + idx);
    cc = (int)(unsigned)pu;
    w = __uint_as_float((unsigned)(pu >> 32));
}

// ---------------- hop 1 (bf16 out): 32 edges/iter, 4 batch-gathers in flight ----------------
// lane = (edge-slot es = lane>>3, graph-group gg = lane&7); self-term only es==0.
__global__ void k_q1_gather(const int* __restrict__ rowptr, const float2* __restrict__ pack,
                            const int* __restrict__ batch, const float* __restrict__ dinv,
                            unsigned short* __restrict__ Q) {
    int wid = (blockIdx.x * blockDim.x + threadIdx.x) >> 6;
    int lane = threadIdx.x & 63;
    if (wid >= NN) return;
    int es = lane >> 3;      // edge slot within 8-batch
    int gg = lane & 7;       // graph group: graphs gg*8 .. gg*8+7
    int beg = rowptr[wid], end = rowptr[wid + 1];
    float d = dinv[wid];
    int bself = batch[wid];
    float dd = d * d;
    float acc[8];
#pragma unroll
    for (int i = 0; i < 8; ++i)
        acc[i] = (es == 0 && bself == gg * 8 + i) ? dd : 0.0f;

    if (beg < end) {
        int last = end - 1;
        for (int e = beg; e < end; e += 32) {
            int i0 = e + es, i1 = e + 8 + es, i2 = e + 16 + es, i3 = e + 24 + es;
            int c0, c1, c2, c3; float w0, w1, w2, w3;
            pk_nt(pack, min(i0, last), c0, w0);
            pk_nt(pack, min(i1, last), c1, w1);
            pk_nt(pack, min(i2, last), c2, w2);
            pk_nt(pack, min(i3, last), c3, w3);
            if (i0 > last) w0 = 0.0f;
            if (i1 > last) w1 = 0.0f;
            if (i2 > last) w2 = 0.0f;
            if (i3 > last) w3 = 0.0f;
            int b0 = batch[c0];
            int b1 = batch[c1];
            int b2 = batch[c2];
            int b3 = batch[c3];
#pragma unroll
            for (int i = 0; i < 8; ++i) {
                int g = gg * 8 + i;
                acc[i] += (b0 == g) ? w0 : 0.0f;
                acc[i] += (b1 == g) ? w1 : 0.0f;
                acc[i] += (b2 == g) ? w2 : 0.0f;
                acc[i] += (b3 == g) ? w3 : 0.0f;
            }
        }
    }
#pragma unroll
    for (int m = 8; m <= 32; m <<= 1)
#pragma unroll
        for (int i = 0; i < 8; ++i) acc[i] += __shfl_xor(acc[i], m, 64);
    if (es == 0) {
        uint4 o;
        o.x = (unsigned)f2bf(acc[0]) | ((unsigned)f2bf(acc[1]) << 16);
        o.y = (unsigned)f2bf(acc[2]) | ((unsigned)f2bf(acc[3]) << 16);
        o.z = (unsigned)f2bf(acc[4]) | ((unsigned)f2bf(acc[5]) << 16);
        o.w = (unsigned)f2bf(acc[6]) | ((unsigned)f2bf(acc[7]) << 16);
        ((uint4*)Q)[(size_t)wid * 8 + gg] = o;
    }
}

// ---------------- hops 2,3 (bf16 in/out): 32 edges/iter, 4 row-gathers in flight ----------------
// Monolithic 64-graph form: at the random-line L2-fill ceiling (~3.6 TB/s on ~330 MB);
// plane-split regressed 4x overhead (round 5) — do not revisit.
__global__ void k_hop_gather(const int* __restrict__ rowptr, const float2* __restrict__ pack,
                             const float* __restrict__ dinv,
                             const unsigned short* __restrict__ Qin,
                             unsigned short* __restrict__ Qout) {
    int wid = (blockIdx.x * blockDim.x + threadIdx.x) >> 6;
    int lane = threadIdx.x & 63;
    if (wid >= NN) return;
    int es = lane >> 3;
    int gg = lane & 7;
    int beg = rowptr[wid], end = rowptr[wid + 1];
    float d = dinv[wid];
    const uint4* Q4 = (const uint4*)Qin;   // row r, group gg at index r*8+gg

    float acc[8];
    if (es == 0) {
        uint4 qs = Q4[(size_t)wid * 8 + gg];
        float dd = d * d;
        acc[0] = dd * __uint_as_float(qs.x << 16);
        acc[1] = dd * __uint_as_float(qs.x & 0xffff0000u);
        acc[2] = dd * __uint_as_float(qs.y << 16);
        acc[3] = dd * __uint_as_float(qs.y & 0xffff0000u);
        acc[4] = dd * __uint_as_float(qs.z << 16);
        acc[5] = dd * __uint_as_float(qs.z & 0xffff0000u);
        acc[6] = dd * __uint_as_float(qs.w << 16);
        acc[7] = dd * __uint_as_float(qs.w & 0xffff0000u);
    } else {
#pragma unroll
        for (int i = 0; i < 8; ++i) acc[i] = 0.0f;
    }

    if (beg < end) {
        int last = end - 1;
        for (int e = beg; e < end; e += 32) {
            int i0 = e + es, i1 = e + 8 + es, i2 = e + 16 + es, i3 = e + 24 + es;
            int c0, c1, c2, c3; float w0, w1, w2, w3;
            pk_nt(pack, min(i0, last), c0, w0);
            pk_nt(pack, min(i1, last), c1, w1);
            pk_nt(pack, min(i2, last), c2, w2);
            pk_nt(pack, min(i3, last), c3, w3);
            if (i0 > last) w0 = 0.0f;
            if (i1 > last) w1 = 0.0f;
            if (i2 > last) w2 = 0.0f;
            if (i3 > last) w3 = 0.0f;
            uint4 q0 = Q4[(size_t)c0 * 8 + gg];
            uint4 q1 = Q4[(size_t)c1 * 8 + gg];
            uint4 q2 = Q4[(size_t)c2 * 8 + gg];
            uint4 q3 = Q4[(size_t)c3 * 8 + gg];
            acc[0] += w0 * __uint_as_float(q0.x << 16);
            acc[1] += w0 * __uint_as_float(q0.x & 0xffff0000u);
            acc[2] += w0 * __uint_as_float(q0.y << 16);
            acc[3] += w0 * __uint_as_float(q0.y & 0xffff0000u);
            acc[4] += w0 * __uint_as_float(q0.z << 16);
            acc[5] += w0 * __uint_as_float(q0.z & 0xffff0000u);
            acc[6] += w0 * __uint_as_float(q0.w << 16);
            acc[7] += w0 * __uint_as_float(q0.w & 0xffff0000u);
            acc[0] += w1 * __uint_as_float(q1.x << 16);
            acc[1] += w1 * __uint_as_float(q1.x & 0xffff0000u);
            acc[2] += w1 * __uint_as_float(q1.y << 16);
            acc[3] += w1 * __uint_as_float(q1.y & 0xffff0000u);
            acc[4] += w1 * __uint_as_float(q1.z << 16);
            acc[5] += w1 * __uint_as_float(q1.z & 0xffff0000u);
            acc[6] += w1 * __uint_as_float(q1.w << 16);
            acc[7] += w1 * __uint_as_float(q1.w & 0xffff0000u);
            acc[0] += w2 * __uint_as_float(q2.x << 16);
            acc[1] += w2 * __uint_as_float(q2.x & 0xffff0000u);
            acc[2] += w2 * __uint_as_float(q2.y << 16);
            acc[3] += w2 * __uint_as_float(q2.y & 0xffff0000u);
            acc[4] += w2 * __uint_as_float(q2.z << 16);
            acc[5] += w2 * __uint_as_float(q2.z & 0xffff0000u);
            acc[6] += w2 * __uint_as_float(q2.w << 16);
            acc[7] += w2 * __uint_as_float(q2.w & 0xffff0000u);
            acc[0] += w3 * __uint_as_float(q3.x << 16);
            acc[1] += w3 * __uint_as_float(q3.x & 0xffff0000u);
            acc[2] += w3 * __uint_as_float(q3.y << 16);
            acc[3] += w3 * __uint_as_float(q3.y & 0xffff0000u);
            acc[4] += w3 * __uint_as_float(q3.z << 16);
            acc[5] += w3 * __uint_as_float(q3.z & 0xffff0000u);
            acc[6] += w3 * __uint_as_float(q3.w << 16);
            acc[7] += w3 * __uint_as_float(q3.w & 0xffff0000u);
        }
    }
#pragma unroll
    for (int m = 8; m <= 32; m <<= 1)
#pragma unroll
        for (int i = 0; i < 8; ++i) acc[i] += __shfl_xor(acc[i], m, 64);
    if (es == 0) {
        uint4 o;
        o.x = (unsigned)f2bf(acc[0]) | ((unsigned)f2bf(acc[1]) << 16);
        o.y = (unsigned)f2bf(acc[2]) | ((unsigned)f2bf(acc[3]) << 16);
        o.z = (unsigned)f2bf(acc[4]) | ((unsigned)f2bf(acc[5]) << 16);
        o.w = (unsigned)f2bf(acc[6]) | ((unsigned)f2bf(acc[7]) << 16);
        ((uint4*)Qout)[(size_t)wid * 8 + gg] = o;
    }
}

// ---------------- pool: per-block partial[g][f] = sum_n Q3[n][g]*x[n][f] ----------------
// 40 KB LDS -> 4 blocks/CU; NO trailing atomics (plain float4 partial stores).
__global__ __launch_bounds__(256) void k_pool(const unsigned short* __restrict__ Q,
                                              const float* __restrict__ x,
                                              float* __restrict__ partial) {
    __shared__ unsigned short qsh[PT * NG];   // 8 KB (bf16)
    __shared__ float xs[PT * NF];             // 32 KB
    int t = threadIdx.x;
    int f4 = (t & 31) << 2;
    int g0 = (t >> 5) << 3;
    float4 acc[8];
#pragma unroll
    for (int i = 0; i < 8; ++i) acc[i] = make_float4(0.f, 0.f, 0.f, 0.f);

    const int NT = (NN + PT - 1) / PT;   // 1563
    for (int tile = blockIdx.x; tile < NT; tile += GP) {
        int n0 = tile * PT;
        int nt = min(PT, NN - n0);
        const uint4*  Q4 = (const uint4*)(Q + (size_t)n0 * NG);
        const float4* X4 = (const float4*)(x + (size_t)n0 * NF);
        uint4*  qs4 = (uint4*)qsh;
        float4* xs4 = (float4*)xs;
        for (int i = t; i < nt * (NG / 8); i += 256) qs4[i] = Q4[i];
        for (int i = t; i < nt * (NF / 4); i += 256) xs4[i] = X4[i];
        __syncthreads();
        for (int n = 0; n < nt; ++n) {
            float4 xv = *(const float4*)&xs[n * NF + f4];
            uint4 qu = *(const uint4*)&qsh[n * NG + g0];
            float qv[8];
            qv[0] = __uint_as_float(qu.x << 16);
            qv[1] = __uint_as_float(qu.x & 0xffff0000u);
            qv[2] = __uint_as_float(qu.y << 16);
            qv[3] = __uint_as_float(qu.y & 0xffff0000u);
            qv[4] = __uint_as_float(qu.z << 16);
            qv[5] = __uint_as_float(qu.z & 0xffff0000u);
            qv[6] = __uint_as_float(qu.w << 16);
            qv[7] = __uint_as_float(qu.w & 0xffff0000u);
#pragma unroll
            for (int i = 0; i < 8; ++i) {
                acc[i].x += qv[i] * xv.x;
                acc[i].y += qv[i] * xv.y;
                acc[i].z += qv[i] * xv.z;
                acc[i].w += qv[i] * xv.w;
            }
        }
        __syncthreads();
    }
    float* pb = partial + (size_t)blockIdx.x * (NG * NF);
#pragma unroll
    for (int i = 0; i < 8; ++i)
        *(float4*)&pb[(g0 + i) * NF + f4] = acc[i];
}

// ---------------- reduce GP partial slabs -> psum (8-way split-K) ----------------
__global__ void k_red(const float* __restrict__ partial, float* __restrict__ psum) {
    int gid = blockIdx.x * blockDim.x + threadIdx.x;   // 65536 threads
    int idx = gid & (NG * NF - 1);
    int j = gid >> 13;                                 // 0..7
    float acc = 0.0f;
    for (int b = j; b < GP; b += 8)
        acc += partial[(size_t)b * (NG * NF) + idx];
    atomicAdd(&psum[idx], acc);
}

// ---------------- final: fold both linears ----------------
__global__ void k_final(const float* __restrict__ psum, const float* __restrict__ cnt,
                        const float* __restrict__ Wc, const float* __restrict__ bc,
                        const float* __restrict__ Wl, const float* __restrict__ bl,
                        float* __restrict__ out) {
    __shared__ float M[NP * NH];
    __shared__ float bias[NP];
    int t = threadIdx.x;
    for (int idx = t; idx < NP * NH; idx += 256) {
        int p = idx >> 7, f = idx & 127;
        float s = 0.0f;
        for (int h = 0; h < NH; ++h) s += Wl[p * NH + h] * Wc[h * NF + f];
        M[idx] = s;
    }
    if (t < NP) {
        float s = bl[t];
        for (int h = 0; h < NH; ++h) s += Wl[t * NH + h] * bc[h];
        bias[t] = s;
    }
    __syncthreads();
    for (int idx = t; idx < NG * NP; idx += 256) {
        int g = idx >> 3, p = idx & 7;
        float inv = 1.0f / fmaxf(cnt[g], 1.0f);
        float s = 0.0f;
        for (int f = 0; f < NF; ++f) s += psum[g * NF + f] * M[p * NH + f];
        out[idx] = s * inv + bias[p];
    }
}

extern "C" void kernel_launch(void* const* d_in, const int* in_sizes, int n_in,
                              void* d_out, int out_size, void* d_ws, size_t ws_size,
                              hipStream_t stream) {
    const float* x     = (const float*)d_in[0];
    const int*   ei    = (const int*)d_in[1];
    const float* ea    = (const float*)d_in[2];
    const int*   batch = (const int*)d_in[3];
    const float* Wc    = (const float*)d_in[4];
    const float* bc    = (const float*)d_in[5];
    const float* Wl    = (const float*)d_in[6];
    const float* bl    = (const float*)d_in[7];
    const int* row = ei;           // edge_index[0]
    const int* col = ei + NE;      // edge_index[1]
    float* out = (float*)d_out;

    // ---- workspace (~77.7 MB footprint, all segments 16 B aligned) ----
    // Scan scratch aliases pack (dead before k_sort writes pack).
    // Qa (bf16) = first half of H block (H dead after k_sort).
    // partial (GP*8192 f32 = 33.6 MB) = Qb half + Hd (both dead before k_pool).
    float* ws     = (float*)d_ws;
    float*  dinv   = ws;                          // NN floats            (400000 B)
    int*    rowptr = (int*)(dinv + NN);           // NN+4 ints            (400016 B)
    float*  cnt    = (float*)(rowptr + NN + 4);   // NG                   (256 B)
    float*  psum   = cnt + NG;                    // NG*NH                (32768 B)
    float2* pack   = (float2*)(psum + NG * NH);   // NE float2            (25.6 MB)
    unsigned* H    = (unsigned*)(pack + NE);      // NW*NN u32            (25.6 MB)
    float*    Hd   = (float*)(H + (size_t)NW * NN); // NW*NN f32          (25.6 MB)
    unsigned short* Qa = (unsigned short*)H;              // NN*64 bf16 (12.8 MB)
    unsigned short* Qb = Qa + (size_t)NN * NG;            // NN*64 bf16 (12.8 MB)
    float* partial = (float*)Qb;                  // GP*NG*NF f32 (33.6 MB, spans Qb+Hd)
    int* rcnt = (int*)pack;                       // scan scratch (aliases pack)
    int* px   = rcnt + SCAN_NBLK * SCAN_B;
    int* bsum = px + SCAN_NBLK * SCAN_B;
    int* bofs = bsum + SCAN_NBLK;

    const int B = 256;
    int gN  = (NN + B - 1) / B;                          // 391
    int gW  = (int)(((long long)NN * 64 + B - 1) / B);   // 25000

    k_init<<<(NG * NH + B - 1) / B, B, 0, stream>>>(cnt, psum);
    k_hist2<<<NC_H * NW, B, 0, stream>>>(row, col, ea, H, Hd);   // 832 blocks
    k_cnt<<<gN, B, 0, stream>>>(batch, cnt);
    k_reduce<<<gN, B, 0, stream>>>(H, Hd, rcnt, dinv);

    k_scan1<<<SCAN_NBLK, SCAN_B, 0, stream>>>(rcnt, px, bsum);
    k_scan2<<<1, 64, 0, stream>>>(bsum, bofs);
    k_scan3<<<(NN + 1 + SCAN_B - 1) / SCAN_B, SCAN_B, 0, stream>>>(px, bofs, rowptr);
    k_base<<<gN, B, 0, stream>>>(rowptr, H);
    k_sort<<<NC_S * NW, B, 0, stream>>>(row, col, ea, H, dinv, pack);   // 640 blocks

    // NOTE: k_q1_gather overwrites the H region (as Qa) — H is dead after k_sort.
    k_q1_gather<<<gW, B, 0, stream>>>(rowptr, pack, batch, dinv, Qa);
    k_hop_gather<<<gW, B, 0, stream>>>(rowptr, pack, dinv, Qa, Qb);
    k_hop_gather<<<gW, B, 0, stream>>>(rowptr, pack, dinv, Qb, Qa);

    // NOTE: k_pool writes partial over Qb+Hd (dead); reads Qa (live).
    k_pool<<<GP, B, 0, stream>>>(Qa, x, partial);
    k_red<<<256, B, 0, stream>>>(partial, psum);
    k_final<<<1, B, 0, stream>>>(psum, cnt, Wc, bc, Wl, bl, out);
}